// Round 1
// baseline (567.163 us; speedup 1.0000x reference)
//
#include <hip/hip_runtime.h>
#include <math.h>

#define NN   65536
#define MM   512
#define CTRLD 128
#define RLEN 518
#define WLEN 1542
#define EPSF 1e-16f

__device__ __forceinline__ float softplusf_(float x){
    return x > 0.f ? x + log1pf(expf(-x)) : log1pf(expf(x));
}
__device__ __forceinline__ float sigmoidf_(float x){ return 1.f/(1.f+expf(-x)); }

// 256-thread deterministic block reduce (sum). Leaves red[] reusable.
__device__ __forceinline__ float blockReduce256(float v, float* red){
    int t = threadIdx.x;
    red[t] = v; __syncthreads();
    for(int s = 128; s; s >>= 1){ if(t < s) red[t] += red[t+s]; __syncthreads(); }
    float r = red[0];
    __syncthreads();
    return r;
}

__device__ __forceinline__ void waveReduce2(float& d, float& n){
    for(int o = 32; o; o >>= 1){
        d += __shfl_down(d, o);
        n += __shfl_down(n, o);
    }
}

// ---------- init: w_prev buffers = 1/N ----------
__global__ void k_init(float* __restrict__ wwn, float* __restrict__ wrn){
    int i = blockIdx.x*256 + threadIdx.x;
    wwn[i] = 1.f/NN;
    wrn[i] = 1.f/NN;
}

// ---------- cont = x @ Wc.T + bc  (4x128) ----------
__global__ void k_cont(const float* __restrict__ x, const float* __restrict__ Wc,
                       const float* __restrict__ bc, float* __restrict__ cont){
    int idx = threadIdx.x;          // 512 threads
    if(idx < 4*CTRLD){
        int t = idx >> 7, c = idx & 127;
        float acc = bc[c];
        const float* xr = x + t*CTRLD;
        const float* wr = Wc + c*CTRLD;
        for(int d = 0; d < CTRLD; ++d) acc += xr[d]*wr[d];
        cont[idx] = acc;
    }
}

// ---------- ow/or for all 4 timesteps ----------
__global__ void k_owor(const float* __restrict__ cont,
                       const float* __restrict__ Ww, const float* __restrict__ bw,
                       const float* __restrict__ Wr, const float* __restrict__ br,
                       float* __restrict__ owAll, float* __restrict__ orAll){
    int idx = blockIdx.x*256 + threadIdx.x;
    if(idx < 4*WLEN){
        int t = idx / WLEN, o = idx % WLEN;
        float acc = bw[o];
        const float* cr = cont + t*CTRLD;
        const float* wr = Ww + o*CTRLD;
        for(int d = 0; d < CTRLD; ++d) acc += cr[d]*wr[d];
        owAll[idx] = acc;
    } else {
        int j = idx - 4*WLEN;
        if(j < 4*RLEN){
            int t = j / RLEN, o = j % RLEN;
            float acc = br[o];
            const float* cr = cont + t*CTRLD;
            const float* wr = Wr + o*CTRLD;
            for(int d = 0; d < CTRLD; ++d) acc += cr[d]*wr[d];
            orAll[j] = acc;
        }
    }
}

// ---------- big pass: dot[i] = mem[i].k, n2[i] = |mem[i]|^2 ----------
// grid NN/4, block 256 (wave per row)
__global__ void k_dotn(const float* __restrict__ mem, const float* __restrict__ kvec,
                       float* __restrict__ dot, float* __restrict__ n2v){
    __shared__ float kk[MM];
    int t = threadIdx.x;
    kk[t] = kvec[t]; kk[t+256] = kvec[t+256];
    __syncthreads();
    int wave = t >> 6, lane = t & 63;
    int row = blockIdx.x*4 + wave;
    const float4* mrow = (const float4*)(mem + (size_t)row*MM);
    const float4* k4 = (const float4*)kk;
    float d = 0.f, n = 0.f;
    #pragma unroll
    for(int h = 0; h < 2; ++h){
        int c = lane + h*64;
        float4 v = mrow[c];
        float4 kv = k4[c];
        d += v.x*kv.x + v.y*kv.y + v.z*kv.z + v.w*kv.w;
        n += v.x*v.x + v.y*v.y + v.z*v.z + v.w*v.w;
    }
    waveReduce2(d, n);
    if(lane == 0){ dot[row] = d; n2v[row] = n; }
}

// ---------- softmax denominator partials ----------
// grid 256, block 256
__global__ void k_z(const float* __restrict__ ov, const float* __restrict__ dot,
                    const float* __restrict__ n2v, float* __restrict__ pZ){
    __shared__ float red[256];
    int t = threadIdx.x;
    float kv0 = ov[t], kv1 = ov[t+256];
    float k2 = blockReduce256(kv0*kv0 + kv1*kv1, red);
    float beta = softplusf_(ov[MM]);
    float skn = sqrtf(k2);
    int i = blockIdx.x*256 + t;
    float a = beta*dot[i]/(sqrtf(n2v[i])*skn + EPSF);
    float z = blockReduce256(expf(a), red);
    if(t == 0) pZ[blockIdx.x] = z;
}

// ---------- unnormalized sharpened weights + sum partials ----------
// grid 256, block 256
__global__ void k_w(const float* __restrict__ ov, const float* __restrict__ dot,
                    const float* __restrict__ n2v, const float* __restrict__ pZ,
                    const float* __restrict__ wprev, float* __restrict__ wun,
                    float* __restrict__ pS){
    __shared__ float red[256];
    int t = threadIdx.x;
    float kv0 = ov[t], kv1 = ov[t+256];
    float k2 = blockReduce256(kv0*kv0 + kv1*kv1, red);
    float Z  = blockReduce256(pZ[t], red);
    float beta  = softplusf_(ov[MM]);
    float g     = sigmoidf_(ov[MM+1]);
    float s0 = ov[MM+2], s1 = ov[MM+3], s2 = ov[MM+4];
    float sm = fmaxf(s0, fmaxf(s1, s2));
    float e0 = expf(s0-sm), e1 = expf(s1-sm), e2 = expf(s2-sm);
    float es = e0+e1+e2;
    s0 = e0/es; s1 = e1/es; s2 = e2/es;
    float gamma = 1.f + softplusf_(ov[MM+5]);
    float skn = sqrtf(k2);
    float invZ = 1.f/Z;
    int i  = blockIdx.x*256 + t;
    int im = (i-1) & (NN-1), ip = (i+1) & (NN-1);
    auto wgf = [&](int j)->float{
        float a = beta*dot[j]/(sqrtf(n2v[j])*skn + EPSF);
        return g*expf(a)*invZ + (1.f-g)*wprev[j];
    };
    float wsv = s0*wgf(im) + s1*wgf(i) + s2*wgf(ip);
    float wu = powf(wsv, gamma);
    wun[i] = wu;
    float S = blockReduce256(wu, red);
    if(t == 0) pS[blockIdx.x] = S;
}

// ---------- fused: memory update + read-address dot/norm ----------
// grid NN/4, block 256 (wave per row)
__global__ void k_upd(const float* __restrict__ msrc, float* __restrict__ mdst,
                      const float* __restrict__ ow, const float* __restrict__ orr,
                      const float* __restrict__ wun, const float* __restrict__ pS,
                      float* __restrict__ wwn,
                      float* __restrict__ dot, float* __restrict__ n2v){
    __shared__ float red[256];
    __shared__ float kk[MM], ee[MM], aa[MM];
    int t = threadIdx.x;
    float S = blockReduce256(pS[t], red);
    float invS = 1.f/(S + EPSF);
    kk[t]     = orr[t];        kk[t+256] = orr[t+256];
    ee[t]     = sigmoidf_(ow[MM+6+t]);      ee[t+256] = sigmoidf_(ow[MM+6+256+t]);
    aa[t]     = ow[2*MM+6+t];  aa[t+256] = ow[2*MM+6+256+t];
    __syncthreads();
    int wave = t >> 6, lane = t & 63;
    int row = blockIdx.x*4 + wave;
    float w = wun[row]*invS;
    if(lane == 0) wwn[row] = w;
    const float4* src = (const float4*)(msrc + (size_t)row*MM);
    float4* dst = (float4*)(mdst + (size_t)row*MM);
    const float4* k4 = (const float4*)kk;
    const float4* e4 = (const float4*)ee;
    const float4* a4 = (const float4*)aa;
    float d = 0.f, n = 0.f;
    #pragma unroll
    for(int h = 0; h < 2; ++h){
        int c = lane + h*64;
        float4 v = src[c];
        float4 ev = e4[c], av = a4[c], kv = k4[c];
        v.x = v.x*(1.f - w*ev.x) + w*av.x;
        v.y = v.y*(1.f - w*ev.y) + w*av.y;
        v.z = v.z*(1.f - w*ev.z) + w*av.z;
        v.w = v.w*(1.f - w*ev.w) + w*av.w;
        dst[c] = v;
        d += v.x*kv.x + v.y*kv.y + v.z*kv.z + v.w*kv.w;
        n += v.x*v.x + v.y*v.y + v.z*v.z + v.w*v.w;
    }
    waveReduce2(d, n);
    if(lane == 0){ dot[row] = d; n2v[row] = n; }
}

// ---------- r partials: rp[b][:] = sum over 64 rows of w[i]*mem[i][:] ----------
// grid 1024, block 256 (thread owns 2 columns)
__global__ void k_rpart(const float* __restrict__ mem, const float* __restrict__ wun,
                        const float* __restrict__ pS, float* __restrict__ wrn,
                        float* __restrict__ rp){
    __shared__ float red[256];
    int t = threadIdx.x;
    float S = blockReduce256(pS[t], red);
    float invS = 1.f/(S + EPSF);
    int r0 = blockIdx.x*64;
    if(t < 64) wrn[r0+t] = wun[r0+t]*invS;
    const float2* m2 = (const float2*)mem;
    float2 acc; acc.x = 0.f; acc.y = 0.f;
    for(int i = 0; i < 64; ++i){
        int row = r0 + i;
        float w = wun[row]*invS;
        float2 v = m2[(size_t)row*256 + t];
        acc.x += w*v.x; acc.y += w*v.y;
    }
    ((float2*)rp)[blockIdx.x*256 + t] = acc;
}

// ---------- reduce r partials ----------
// grid 512 (one per column), block 256
__global__ void k_rsum(const float* __restrict__ rp, float* __restrict__ rvec){
    __shared__ float red[256];
    int col = blockIdx.x, t = threadIdx.x;
    float s = rp[(size_t)t*512 + col] + rp[(size_t)(t+256)*512 + col]
            + rp[(size_t)(t+512)*512 + col] + rp[(size_t)(t+768)*512 + col];
    float r = blockReduce256(s, red);
    if(t == 0) rvec[col] = r;
}

// ---------- final MLP ----------
__global__ void k_final(const float* __restrict__ cont, const float* __restrict__ rvec,
                        const float* __restrict__ W1, const float* __restrict__ b1,
                        const float* __restrict__ W2, const float* __restrict__ b2,
                        float* __restrict__ out, int step){
    __shared__ float conc[640];
    __shared__ float h[200];
    int t = threadIdx.x;
    for(int q = t; q < 640; q += 256)
        conc[q] = (q < 128) ? cont[step*128 + q] : rvec[q - 128];
    __syncthreads();
    if(t < 200){
        float acc = b1[t];
        const float* wr = W1 + t*640;
        for(int q = 0; q < 640; ++q) acc += wr[q]*conc[q];
        h[t] = fmaxf(acc, 0.f);
    }
    __syncthreads();
    if(t < 10){
        float acc = b2[t];
        const float* wr = W2 + t*200;
        for(int p = 0; p < 200; ++p) acc += wr[p]*h[p];
        out[step*10 + t] = acc;
    }
}

extern "C" void kernel_launch(void* const* d_in, const int* in_sizes, int n_in,
                              void* d_out, int out_size, void* d_ws, size_t ws_size,
                              hipStream_t stream) {
    const float* x    = (const float*)d_in[0];
    const float* mem0 = (const float*)d_in[1];
    const float* Wc   = (const float*)d_in[2];
    const float* bc   = (const float*)d_in[3];
    const float* Wr   = (const float*)d_in[4];
    const float* br   = (const float*)d_in[5];
    const float* Ww   = (const float*)d_in[6];
    const float* bw   = (const float*)d_in[7];
    const float* W1   = (const float*)d_in[8];
    const float* b1   = (const float*)d_in[9];
    const float* W2   = (const float*)d_in[10];
    const float* b2   = (const float*)d_in[11];
    float* out = (float*)d_out;

    float* ws = (float*)d_ws;
    size_t off = 0;
    float* memw  = ws + off; off += (size_t)NN*MM;   // 128 MiB
    float* dot   = ws + off; off += NN;
    float* n2v   = ws + off; off += NN;
    float* wun   = ws + off; off += NN;
    float* wwn   = ws + off; off += NN;
    float* wrn   = ws + off; off += NN;
    float* pZ    = ws + off; off += 256;
    float* pS    = ws + off; off += 256;
    float* cont  = ws + off; off += 4*CTRLD;
    float* owAll = ws + off; off += 4*WLEN;
    float* orAll = ws + off; off += 4*RLEN;
    float* rp    = ws + off; off += (size_t)1024*512; // 2 MiB
    float* rvec  = ws + off; off += 512;

    k_init<<<256, 256, 0, stream>>>(wwn, wrn);
    k_cont<<<1, 512, 0, stream>>>(x, Wc, bc, cont);
    k_owor<<<33, 256, 0, stream>>>(cont, Ww, bw, Wr, br, owAll, orAll);

    for(int t = 0; t < 4; ++t){
        const float* ow  = owAll + t*WLEN;
        const float* orr = orAll + t*RLEN;
        const float* msrc = (t == 0) ? mem0 : memw;

        // write addressing on pre-update memory
        k_dotn<<<NN/4, 256, 0, stream>>>(msrc, ow, dot, n2v);
        k_z  <<<256, 256, 0, stream>>>(ow, dot, n2v, pZ);
        k_w  <<<256, 256, 0, stream>>>(ow, dot, n2v, pZ, wwn, wun, pS);
        // memory update fused with read-address dot/norm on updated memory
        k_upd<<<NN/4, 256, 0, stream>>>(msrc, memw, ow, orr, wun, pS, wwn, dot, n2v);
        k_z  <<<256, 256, 0, stream>>>(orr, dot, n2v, pZ);
        k_w  <<<256, 256, 0, stream>>>(orr, dot, n2v, pZ, wrn, wun, pS);
        // r = w_r @ mem (also stores normalized w_r for next step)
        k_rpart<<<1024, 256, 0, stream>>>(memw, wun, pS, wrn, rp);
        k_rsum <<<512, 256, 0, stream>>>(rp, rvec);
        k_final<<<1, 256, 0, stream>>>(cont, rvec, W1, b1, W2, b2, out, t);
    }
    (void)in_sizes; (void)n_in; (void)out_size; (void)ws_size;
}